// Round 15
// baseline (1908.887 us; speedup 1.0000x reference)
//
#include <hip/hip_runtime.h>
#include <hip/hip_bf16.h>

// CirculantElmanCell: T=1024, B=16, D=2048
// out0: output [T,B,D] f32 ; out1: h [T+1,B,D] f32 (concatenated in d_out)

typedef __attribute__((ext_vector_type(8))) unsigned short us8;
typedef __attribute__((ext_vector_type(8))) __bf16 bf16x8;
typedef __attribute__((ext_vector_type(4))) float f32x4;
typedef __attribute__((ext_vector_type(2))) float f32x2;

#if __has_builtin(__builtin_amdgcn_permlane32_swap) && __has_builtin(__builtin_amdgcn_permlane16_swap)
#define USE_PL 1
#else
#define USE_PL 0
#endif

__device__ __forceinline__ int SIGF(int a){ return a ^ (((a >> 8) & 3) << 2) ^ ((a >> 6) & 3); }
__device__ __forceinline__ int rev2i(int v){ return ((v & 1) << 1) | ((v >> 1) & 1); }
__device__ __forceinline__ int PERMF(int i){
  return rev2i((i >> 8) & 3) | (rev2i((i >> 6) & 3) << 2) | (rev2i((i >> 4) & 3) << 4)
       | (rev2i((i >> 2) & 3) << 6) | (rev2i(i & 3) << 8);
}

// LDS-only barrier: no vmcnt drain (global loads/stores stay in flight)
#define LDSBAR() do { \
  asm volatile("s_waitcnt lgkmcnt(0)\n\ts_barrier" ::: "memory"); \
  __builtin_amdgcn_sched_barrier(0); \
} while (0)

__device__ __forceinline__ unsigned short f2bf(float f){
  unsigned int u = __float_as_uint(f);
  return (unsigned short)((u + 0x7FFFu + ((u >> 16) & 1u)) >> 16);
}

__device__ __forceinline__ void sincos2pi(float fr, float& sn, float& co){
#if __has_builtin(__builtin_amdgcn_sinf) && __has_builtin(__builtin_amdgcn_cosf)
  sn = __builtin_amdgcn_sinf(fr);   // v_sin_f32: revolutions
  co = __builtin_amdgcn_cosf(fr);
#else
  __sincosf(fr * 6.28318530717958647692f, &sn, &co);
#endif
}

__device__ __forceinline__ float2 cmul(float2 a, float2 b){
  return make_float2(a.x*b.x - a.y*b.y, a.x*b.y + a.y*b.x);
}
__device__ __forceinline__ float2 cmulc(float2 a, float2 b){   // a * conj(b)
  return make_float2(a.x*b.x + a.y*b.y, a.y*b.x - a.x*b.y);
}
__device__ __forceinline__ float2 cadd(float2 a, float2 b){ return make_float2(a.x+b.x, a.y+b.y); }
__device__ __forceinline__ float2 csub(float2 a, float2 b){ return make_float2(a.x-b.x, a.y-b.y); }

__device__ __forceinline__ float tanh_fast(float x){
  float e = __expf(2.0f * x);
  return 1.0f - 2.0f / (e + 1.0f);
}

__device__ __forceinline__ float2 wn(int num, float dinv, int sgn){
  float sn, co; sincos2pi((float)num * dinv, sn, co);
  return make_float2(co, sgn > 0 ? sn : -sn);
}

// ---------------- packed-f32 complex primitives (VOP3P, verified R13/R14) ----------------
__device__ __forceinline__ f32x2 tov(float2 a){ f32x2 r; r[0] = a.x; r[1] = a.y; return r; }
__device__ __forceinline__ float2 tof(f32x2 a){ return make_float2(a[0], a[1]); }

__device__ __forceinline__ float2 pk_fma2(float2 a, float2 b, float2 c){
  f32x2 A = tov(a), B = tov(b), C = tov(c), D;
  asm("v_pk_fma_f32 %0, %1, %2, %3" : "=v"(D) : "v"(A), "v"(B), "v"(C));
  return tof(D);
}
__device__ __forceinline__ float2 pk_cmul(float2 C, float2 z){
  f32x2 Cv = tov(C), Zv = tov(z), D;
  asm("v_pk_mul_f32 %0, %1, %2 op_sel:[0,0] op_sel_hi:[1,0]\n\t"
      "v_pk_fma_f32 %0, %1, %2, %0 op_sel:[1,1,0] op_sel_hi:[0,1,1] neg_lo:[1,0,0]"
      : "=&v"(D) : "v"(Cv), "v"(Zv));
  return tof(D);
}
__device__ __forceinline__ void pk_cfma(float2& acc, float2 C, float2 z){
  f32x2 A = tov(acc), Cv = tov(C), Zv = tov(z);
  asm("v_pk_fma_f32 %0, %1, %2, %0 op_sel:[0,0,0] op_sel_hi:[1,0,1]\n\t"
      "v_pk_fma_f32 %0, %1, %2, %0 op_sel:[1,1,0] op_sel_hi:[0,1,1] neg_lo:[1,0,0]"
      : "+v"(A) : "v"(Cv), "v"(Zv));
  acc = tof(A);
}
__device__ __forceinline__ float2 pk_cmulc(float2 V, float2 m){
  f32x2 Vv = tov(V), Mv = tov(m), D;
  asm("v_pk_mul_f32 %0, %1, %2 op_sel:[0,0] op_sel_hi:[1,0]\n\t"
      "v_pk_fma_f32 %0, %1, %2, %0 op_sel:[1,1,0] op_sel_hi:[0,1,1] neg_hi:[1,0,0]"
      : "=&v"(D) : "v"(Vv), "v"(Mv));
  return tof(D);
}
__device__ __forceinline__ void pk_cfmac(float2& acc, float2 V, float2 m){
  f32x2 A = tov(acc), Vv = tov(V), Mv = tov(m);
  asm("v_pk_fma_f32 %0, %1, %2, %0 op_sel:[0,0,0] op_sel_hi:[1,0,1]\n\t"
      "v_pk_fma_f32 %0, %1, %2, %0 op_sel:[1,1,0] op_sel_hi:[0,1,1] neg_hi:[1,0,0]"
      : "+v"(A) : "v"(Vv), "v"(Mv));
  acc = tof(A);
}

// ---------------- cross-lane exchange primitives ----------------
template<int CTRL>
__device__ __forceinline__ float2 dpp2(float2 v){
  float2 r;
  r.x = __int_as_float(__builtin_amdgcn_mov_dpp(__float_as_int(v.x), CTRL, 0xF, 0xF, true));
  r.y = __int_as_float(__builtin_amdgcn_mov_dpp(__float_as_int(v.y), CTRL, 0xF, 0xF, true));
  return r;
}
template<int IMM>
__device__ __forceinline__ float2 swz2(float2 v){
  float2 r;
  r.x = __int_as_float(__builtin_amdgcn_ds_swizzle(__float_as_int(v.x), IMM));
  r.y = __int_as_float(__builtin_amdgcn_ds_swizzle(__float_as_int(v.y), IMM));
  return r;
}
__device__ __forceinline__ float2 bperm2(int addr, float2 v){
  float2 r;
  r.x = __int_as_float(__builtin_amdgcn_ds_bpermute(addr, __float_as_int(v.x)));
  r.y = __int_as_float(__builtin_amdgcn_ds_bpermute(addr, __float_as_int(v.y)));
  return r;
}
#define DPP_XOR1 0xB1   // quad_perm [1,0,3,2]
#define DPP_XOR2 0x4E   // quad_perm [2,3,0,1]
#define DPP_ROR8 0x128  // row_ror:8 == lane^8 within 16-lane rows

#if USE_PL
typedef __attribute__((ext_vector_type(2))) unsigned int u32x2v;
// with src=dst=T: r[0] = T[l&31] (low-bcast), r[1] = T[l|32] (high-bcast) per ISA docs
__device__ __forceinline__ void pl32(float t, float& L, float& H){
  u32x2v r = __builtin_amdgcn_permlane32_swap(__float_as_uint(t), __float_as_uint(t), false, false);
  L = __uint_as_float(r[0]); H = __uint_as_float(r[1]);
}
// with src=dst=T: r[0] = T[l&~16] (even-row bcast), r[1] = T[l|16] (odd-row bcast)
__device__ __forceinline__ void pl16(float t, float& E, float& O){
  u32x2v r = __builtin_amdgcn_permlane16_swap(__float_as_uint(t), __float_as_uint(t), false, false);
  E = __uint_as_float(r[0]); O = __uint_as_float(r[1]);
}
#endif

// ---------------- folded butterfly core: packed (verified R13/R14) ----------------
template<int CONJ>
__device__ __forceinline__ float2 fold2(float2 u, float2 v, float2 C1, float2 C2){
  if (!CONJ){
    float2 d = pk_cmul(C1, u);
    pk_cfma(d, C2, v);
    return d;
  } else {
    float2 d = pk_cmulc(u, C1);
    pk_cfmac(d, v, C2);
    return d;
  }
}

template<int POS>
__device__ __forceinline__ float2 lds4f(const float2* buf, int a0, int a1, int a2, int a3,
                                        float2 sBv, float2 C1, float2 C2){
  float2 in0 = buf[a0], in1 = buf[a1], in2 = buf[a2], in3 = buf[a3];
  float2 u = pk_fma2(in2, sBv, in0);
  float2 v = pk_fma2(in3, sBv, in1);
  return fold2<POS>(u, v, C1, C2);
}

// Three cross-lane stages. d=16 via permlane swaps (VALU), d=4 round1 via DPP row_ror:8,
// d=4 round2 via ds_swizzle (only remaining DS op), d=1 via quad DPP.
// E1/E2 are pre-swapped at setup for bit4 (and probe direction); G1/G2 carry the
// pl32-direction sign fix (uniform per-thread +-1 factors out linearly to stage output).
template<int POS>
__device__ __forceinline__ float2 lanes3f(float2 T, int bpa,
    float2 sH2v, float2 E1, float2 E2,
    float2 sH3v, float2 F1, float2 F2,
    float2 sH4v, float2 G1, float2 G2){
#if USE_PL
  { // d=16: lane^32 then lane^16, all VALU
    float Lx, Hx, Ly, Hy;
    pl32(T.x, Lx, Hx); pl32(T.y, Ly, Hy);
    T = pk_fma2(make_float2(Hx, Hy), sH2v, make_float2(Lx, Ly));   // L + sH2*H
    float Ex, Ox, Ey, Oy;
    pl16(T.x, Ex, Ox); pl16(T.y, Ey, Oy);
    T = fold2<POS>(make_float2(Ex, Ey), make_float2(Ox, Oy), E1, E2);
  }
#else
  { float2 par = bperm2(bpa, T);
    T = pk_fma2(T, sH2v, par);
    float2 p2 = swz2<0x401F>(T);
    T = fold2<POS>(T, p2, E1, E2); }
#endif
  { // d=4: lane^8 (DPP), lane^4 (swizzle)
    float2 par = dpp2<DPP_ROR8>(T);
    T = pk_fma2(T, sH3v, par);
    float2 p2 = swz2<0x101F>(T);
    T = fold2<POS>(T, p2, F1, F2); }
  { // d=1: quad DPP
    float2 par = dpp2<DPP_XOR2>(T);
    T = pk_fma2(T, sH4v, par);
    float2 p2 = dpp2<DPP_XOR1>(T);
    T = fold2<POS>(T, p2, G1, G2); }
  return T;
}

// ---------------- per-thread constants ----------------
struct TW {
  float2 A1, A2, B1, B2;
  float2 E1, E2, F1, F2, G1, G2;
  float2 wmd;
  float2 sB0v, sB1v, sH2v, sH3v, sH4v;
  float sB0;
  int sfi, swP, smir, bpa;
  int aA0, aA1, aA2, aA3, aB0, aB1, aB2, aB3;
  int aM0, aM1, aM2, aM3;
};

__device__ __forceinline__ float2 scal(float2 a, float s){ return make_float2(a.x*s, a.y*s); }

__device__ __forceinline__ void make_tw(int i, TW& S){
  const int p0 = rev2i((i >> 8) & 3);
  const int p1 = rev2i((i >> 6) & 3);
  const int p2v = rev2i((i >> 4) & 3);
  const int p3v = rev2i((i >> 2) & 3);
  const float2 tw0 = wn(((i & 255) * p0) & 1023, 1.0f/1024.0f, -1);
  const float2 tw1 = wn(((i & 63) * p1) & 255, 1.0f/256.0f, -1);
  const float2 tw2 = wn(((i & 15) * p2v) & 63, 1.0f/64.0f, -1);
  const float2 tw3 = wn(((i & 3) * p3v) & 15, 1.0f/16.0f, -1);
  S.wmd = wn(i & 2047, 1.0f/2048.0f, -1);
  const float sD0 = (p0 & 2) ? -1.f : 1.f;  const bool sel0 = p0 & 1;
  const float sD1 = (p1 & 2) ? -1.f : 1.f;  const bool sel1 = p1 & 1;
  const float sB0 = (p0 & 1) ? -1.f : 1.f;
  const float sB1 = (p1 & 1) ? -1.f : 1.f;
  S.sB0 = sB0;
  S.sB0v = make_float2(sB0, sB0);
  S.sB1v = make_float2(sB1, sB1);
  const float2 rho0 = sel0 ? make_float2(0.f,-1.f) : make_float2(1.f,0.f);
  const float2 rho1 = sel1 ? make_float2(0.f,-1.f) : make_float2(1.f,0.f);
  S.A1 = tw0; S.A2 = scal(cmul(tw0, rho0), sD0);
  S.B1 = tw1; S.B2 = scal(cmul(tw1, rho1), sD1);
  const bool c02 = (i >> 4) & 1, c12 = (i >> 5) & 1;
  const bool c03 = (i >> 2) & 1, c13 = (i >> 3) & 1;
  const bool c04 = i & 1,        c14 = (i >> 1) & 1;
  const float sH2 = c12 ? -1.f : 1.f;
  const float sH3 = c13 ? -1.f : 1.f;
  const float sH4 = c14 ? -1.f : 1.f;
  S.sH2v = make_float2(sH2, sH2);
  S.sH3v = make_float2(sH3, sH3);
  S.sH4v = make_float2(sH4, sH4);
  {
    const float sL = c02 ? -1.f : 1.f;
    const float2 rho = c12 ? make_float2(0.f,-1.f) : make_float2(1.f,0.f);
    const float2 al = c02 ? scal(rho, sL) : make_float2(1.f,0.f);
    const float2 be = c02 ? make_float2(1.f,0.f) : scal(rho, sL);
    S.E1 = cmul(tw2, al); S.E2 = cmul(tw2, be);
  }
  {
    const float sL = c03 ? -1.f : 1.f;
    const float2 rho = c13 ? make_float2(0.f,-1.f) : make_float2(1.f,0.f);
    const float2 al = c03 ? scal(rho, sL) : make_float2(1.f,0.f);
    const float2 be = c03 ? make_float2(1.f,0.f) : scal(rho, sL);
    S.F1 = cmul(tw3, al); S.F2 = cmul(tw3, be);
  }
  {
    const float sL = c04 ? -1.f : 1.f;
    const float2 rho = c14 ? make_float2(0.f,-1.f) : make_float2(1.f,0.f);
    S.G1 = c04 ? scal(rho, sL) : make_float2(1.f,0.f);
    S.G2 = c04 ? make_float2(1.f,0.f) : scal(rho, sL);
  }
#if USE_PL
  {
    // setup-time direction probes (insurance against swap-direction misread)
    const int lane = i & 63;
    float L0, H0; pl32((float)lane, L0, H0);
    const bool flip32 = (L0 != (float)(lane & 31));
    // flipped pl32 => round1 output negated exactly on bit5 lanes (uniform per-thread),
    // which propagates linearly to the stage output; absorb into G1/G2 (s^2 = 1).
    if (flip32 && ((lane >> 5) & 1)){ S.G1 = scal(S.G1, -1.f); S.G2 = scal(S.G2, -1.f); }
    float E0, O0; pl16((float)lane, E0, O0);
    const bool flip16 = (E0 != (float)(lane & ~16));
    // fold2(r0, r1, C1, C2): swap constants when own-value sits in r1
    if (c02 != flip16){ float2 t = S.E1; S.E1 = S.E2; S.E2 = t; }
  }
#endif
  S.sfi = SIGF(i); S.swP = SIGF(PERMF(i)); S.smir = SIGF((1024 - i) & 1023);
  S.bpa = ((i & 63) ^ 32) << 2;
  const int r256 = i & 255;
  S.aA0 = SIGF(r256); S.aA1 = SIGF(r256 + 256); S.aA2 = SIGF(r256 + 512); S.aA3 = SIGF(r256 + 768);
  const int b64 = (i & ~255) + (i & 63);
  S.aB0 = SIGF(b64); S.aB1 = SIGF(b64 + 64); S.aB2 = SIGF(b64 + 128); S.aB3 = SIGF(b64 + 192);
  S.aM0 = SIGF((1024 - r256) & 1023);
  S.aM1 = SIGF((1024 - (r256 + 256)) & 1023);
  S.aM2 = SIGF((1024 - (r256 + 512)) & 1023);
  S.aM3 = SIGF((1024 - (r256 + 768)) & 1023);
}

// 5-phase conv body (R13/R14-verified structure). Result at bB[S.sfi].
__device__ __forceinline__ void fftconv5(float2* hz, float2* bA, float2* bB,
                                         const TW& S, const float2* U, const float2* V){
  float2 T = lds4f<0>(hz, S.aA0, S.aA1, S.aA2, S.aA3, S.sB0v, S.A1, S.A2);
  bA[S.sfi] = T; LDSBAR();
  T = lds4f<0>(bA, S.aB0, S.aB1, S.aB2, S.aB3, S.sB1v, S.B1, S.B2);
  T = lanes3f<0>(T, S.bpa, S.sH2v, S.E1, S.E2, S.sH3v, S.F1, S.F2, S.sH4v, S.G1, S.G2);
  bB[S.swP] = T; LDSBAR();
  {
    float2 z0 = bB[S.aA0], z1 = bB[S.aA1], z2 = bB[S.aA2], z3 = bB[S.aA3];
    float2 m0 = bB[S.aM0], m1 = bB[S.aM1], m2 = bB[S.aM2], m3 = bB[S.aM3];
    float2 y = pk_cmul(U[0], z0);
    pk_cfma(y, U[1], z1);
    pk_cfma(y, U[2], z2);
    pk_cfma(y, U[3], z3);
    pk_cfmac(y, V[0], m0);
    pk_cfmac(y, V[1], m1);
    pk_cfmac(y, V[2], m2);
    pk_cfmac(y, V[3], m3);
    bA[S.sfi] = y;
  }
  LDSBAR();
  T = lds4f<1>(bA, S.aB0, S.aB1, S.aB2, S.aB3, S.sB1v, S.B1, S.B2);
  T = lanes3f<1>(T, S.bpa, S.sH2v, S.E1, S.E2, S.sH3v, S.F1, S.F2, S.sH4v, S.G1, S.G2);
  bB[S.swP] = T; LDSBAR();
}

// in-block lam + P/Q from real 2048-seq c (verified R9-R14)
__device__ __forceinline__ void make_PQ(const float* __restrict__ c, int i, const TW& S,
                                        float2* hz, float2* bA, float2* bB,
                                        float2& P, float2& Q){
  hz[S.sfi] = ((const float2*)c)[i];
  __syncthreads();
  float2 T = lds4f<0>(hz, S.aA0, S.aA1, S.aA2, S.aA3, S.sB0v, S.A1, S.A2);
  bA[S.sfi] = T;
  __syncthreads();
  T = lds4f<0>(bA, S.aB0, S.aB1, S.aB2, S.aB3, S.sB1v, S.B1, S.B2);
  T = lanes3f<0>(T, S.bpa, S.sH2v, S.E1, S.E2, S.sH3v, S.F1, S.F2, S.sH4v, S.G1, S.G2);
  bB[S.swP] = T;
  __syncthreads();
  float2 zk = bB[S.sfi], zp = bB[S.smir];
  float2 E = make_float2(0.5f*(zk.x+zp.x),  0.5f*(zk.y-zp.y));
  float2 O = make_float2(0.5f*(zk.y+zp.y), -0.5f*(zk.x-zp.x));
  float2 w = S.wmd;
  float2 wO = cmul(w, O);
  float2 lamA = scal(cadd(E, wO), 1.0f/2048.0f);
  float2 lamB = scal(csub(E, wO), 1.0f/2048.0f);
  float2 al = make_float2(0.5f*(1.0f + w.y), -0.5f*w.x);
  float2 be = make_float2(0.5f*(1.0f - w.y),  0.5f*w.x);
  float2 ga = make_float2(1.0f + w.y,  w.x);
  float2 de = make_float2(1.0f - w.y, -w.x);
  float2 gA = cmul(ga, lamA), dB = cmul(de, lamB);
  P = cadd(cmul(gA, al), cmul(dB, be));
  Q = cadd(cmul(gA, be), cmul(dB, al));
  __syncthreads();
}

// stage P,Q through LDS and gather per-thread U/V for the fused phase
__device__ __forceinline__ void make_UV(int i, const TW& S, float2 P, float2 Q,
                                        float2* bA, float2* bB, float2* U, float2* V){
  ((float2*)bB)[i] = P;
  ((float2*)bA)[i] = Q;
  __syncthreads();
  const int r256 = i & 255;
  const float2 cA1 = make_float2(S.A1.x, -S.A1.y);
  const float2 cA2 = make_float2(S.A2.x, -S.A2.y);
  float2 cc[4];
  cc[0] = cA1; cc[1] = cA2; cc[2] = scal(cA1, S.sB0); cc[3] = scal(cA2, S.sB0);
  #pragma unroll
  for (int q = 0; q < 4; ++q){
    const int n = r256 + 256 * q;
    U[q] = cmul(cc[q], ((float2*)bB)[n]);
    V[q] = cmul(cc[q], ((float2*)bA)[n]);
  }
  __syncthreads();
}

// ---------------- f32 -> bf16 bulk convert (R8-proven) ----------------
__global__ __launch_bounds__(256) void cvt_bf16(const float* __restrict__ in,
                                                unsigned short* __restrict__ out, int n8){
  int i = blockIdx.x * 256 + threadIdx.x;
  if (i >= n8) return;
  float4 a = ((const float4*)in)[2 * i];
  float4 b = ((const float4*)in)[2 * i + 1];
  us8 r;
  r[0] = f2bf(a.x); r[1] = f2bf(a.y); r[2] = f2bf(a.z); r[3] = f2bf(a.w);
  r[4] = f2bf(b.x); r[5] = f2bf(b.y); r[6] = f2bf(b.z); r[7] = f2bf(b.w);
  ((us8*)out)[i] = r;
}

// =====================================================================
// mega v10 = R14 + cross-lane exchanges moved off the DS pipe
// (permlane32_swap / permlane16_swap / DPP row_ror:8).
// blocks [0,16) recur ; [16,144) circx ; [144,1168) gemm (4 tiles each, bf16).
// =====================================================================
__global__ __launch_bounds__(1024, 4) void mega(
    const float* __restrict__ x, const unsigned short* __restrict__ xb,
    const unsigned short* __restrict__ Wb, const float* __restrict__ h0,
    const float* __restrict__ ch, const float* __restrict__ cx,
    const float* __restrict__ bias, const float* __restrict__ bg,
    float* __restrict__ outp, float* __restrict__ houtp, int* __restrict__ flags){
  __shared__ __align__(16) char smem[98304];   // 96KB: forces 1 block/CU
  const int bid = blockIdx.x;
  const int tid = threadIdx.x;
  int* gcnt = flags;
  int* wcnt = flags + 128;

  if (bid < 16){
    // ---------------- recur consumer (dedicated CU) ----------------
    float2* hz = (float2*)smem; float2* bA = hz + 1024; float2* bB = hz + 2048;
    const int i = tid, b = bid;
    TW S; make_tw(i, S);
    float2 P, Q; make_PQ(ch, i, S, hz, bA, bB, P, Q);
    float2 U[4], V[4]; make_UV(i, S, P, Q, bA, bB, U, V);
    {
      const float2* h02 = (const float2*)(h0 + (size_t)b * 2048);
      float2* hrow0 = (float2*)(houtp + (size_t)b * 2048);
      float2 v = h02[i]; hz[S.sfi] = v; hrow0[i] = v;
    }
    __syncthreads();
    int pg = 0, pw = 0;   // prefetched flag values (tid0 only)
    #pragma unroll 1
    for (int t = 0; t < 1024; ++t){
      if ((t & 7) == 0){
        if (tid == 0){
          const int xk = t >> 3;
          while (pg < 32){
            pg = __hip_atomic_load(&gcnt[xk], __ATOMIC_RELAXED, __HIP_MEMORY_SCOPE_SYSTEM);
            if (pg < 32) __builtin_amdgcn_s_sleep(16);
          }
          while (pw < 128){
            pw = __hip_atomic_load(&wcnt[xk], __ATOMIC_RELAXED, __HIP_MEMORY_SCOPE_SYSTEM);
            if (pw < 128) __builtin_amdgcn_s_sleep(16);
          }
          if (xk < 127){   // prefetch next chunk; latency hides across 8 steps
            pg = __hip_atomic_load(&gcnt[xk + 1], __ATOMIC_RELAXED, __HIP_MEMORY_SCOPE_SYSTEM);
            pw = __hip_atomic_load(&wcnt[xk + 1], __ATOMIC_RELAXED, __HIP_MEMORY_SCOPE_SYSTEM);
          }
        }
        __syncthreads();
      }
      float* orow = outp  + ((size_t)t * 16 + b) * 2048;
      float* hrow = houtp + ((size_t)(t + 1) * 16 + b) * 2048;
      unsigned long long pv = __hip_atomic_load((const unsigned long long*)(orow + 2*i),
                                                __ATOMIC_RELAXED, __HIP_MEMORY_SCOPE_SYSTEM);
      unsigned long long gvv = __hip_atomic_load((const unsigned long long*)(hrow + 2*i),
                                                 __ATOMIC_RELAXED, __HIP_MEMORY_SCOPE_SYSTEM);
      float2 pr = __builtin_bit_cast(float2, pv);
      float2 gv = __builtin_bit_cast(float2, gvv);
      fftconv5(hz, bA, bB, S, U, V);
      float2 y = bB[S.sfi];
      float hx = tanh_fast(y.x + pr.x);
      float hy = tanh_fast(y.y + pr.y);
      float ox = hx * gv.x, oy = hy * gv.y;
      asm volatile("" : "+v"(hx), "+v"(hy) : "v"(gv.x), "v"(gv.y));
      float2 hv = make_float2(hx, hy);
      hz[S.sfi] = hv;
      *(float2*)(hrow + 2 * i) = hv;
      *(float2*)(orow + 2 * i) = make_float2(ox, oy);
      LDSBAR();
    }
  } else if (bid < 144){
    // ---------------- circx producer: rows cblk + 128*k ----------------
    float2* hz = (float2*)smem; float2* bA = hz + 1024; float2* bB = hz + 2048;
    const int i = tid, cblk = bid - 16;
    TW S; make_tw(i, S);
    float2 P, Q; make_PQ(cx, i, S, hz, bA, bB, P, Q);
    float2 U[4], V[4]; make_UV(i, S, P, Q, bA, bB, U, V);
    const float2 bv = ((const float2*)bias)[i];
    #pragma unroll 1
    for (int k = 0; k < 128; ++k){
      const size_t row = (size_t)cblk + ((size_t)k << 7);
      hz[S.sfi] = ((const float2*)(x + row * 2048))[i];
      LDSBAR();
      fftconv5(hz, bA, bB, S, U, V);
      float2 y = bB[S.sfi];
      float* pd = outp + row * 2048 + 2 * i;
      float2 yv = make_float2(y.x + bv.x, y.y + bv.y);
      __hip_atomic_store((unsigned long long*)pd, __builtin_bit_cast(unsigned long long, yv),
                         __ATOMIC_RELAXED, __HIP_MEMORY_SCOPE_SYSTEM);
      __syncthreads();   // vmcnt(0) drain: stores complete at L3 before flag
      if (tid == 0)
        __hip_atomic_fetch_add(&wcnt[k], 1, __ATOMIC_RELAXED, __HIP_MEMORY_SCOPE_SYSTEM);
    }
  } else {
    // ---------------- gemm producer: 4 tiles 128x64, bf16, LDA=40 pad (R8-proven) ----------------
    const int q = bid - 144;
    const int g = tid >> 8, tid8 = tid & 255;
    const int tau = q * 4 + g;
    const int m0 = (tau >> 5) * 128, n0 = (tau & 31) * 64;
    unsigned short* As = (unsigned short*)(smem + g * 15360);   // 128 x 40 (padded)
    unsigned short* Bs = As + 5120;                             // 64 x 40
    const int lane = tid8 & 63, wave = tid8 >> 6;
    const int srA = tid8 >> 1, scA = (tid8 & 1) << 4;
    const int srB = tid8 >> 2, scB = (tid8 & 3) << 3;
    const unsigned short* ga = xb + (size_t)(m0 + srA) * 2048 + scA;
    const unsigned short* gb = Wb + (size_t)(n0 + srB) * 2048 + scB;
    unsigned short* la = As + srA * 40 + scA;
    unsigned short* lb = Bs + srB * 40 + scB;
    f32x4 acc[2][4];
    #pragma unroll
    for (int m = 0; m < 2; ++m)
      #pragma unroll
      for (int n = 0; n < 4; ++n)
        acc[m][n] = f32x4{0.f, 0.f, 0.f, 0.f};
    const int arow = wave * 32 + (lane & 15);
    const int brow = lane & 15;
    const int koff = (lane >> 4) * 8;
    for (int ks = 0; ks < 64; ++ks){
      const int k0 = ks * 32;
      us8 va0 = *(const us8*)(ga + k0);
      us8 va1 = *(const us8*)(ga + k0 + 8);
      us8 vb0 = *(const us8*)(gb + k0);
      __syncthreads();
      *(us8*)(la)     = va0; *(us8*)(la + 8) = va1;
      *(us8*)(lb)     = vb0;
      __syncthreads();
      bf16x8 av[2], bvv[4];
      #pragma unroll
      for (int m = 0; m < 2; ++m) av[m] = *(const bf16x8*)(As + (arow + m * 16) * 40 + koff);
      #pragma unroll
      for (int n = 0; n < 4; ++n) bvv[n] = *(const bf16x8*)(Bs + (brow + n * 16) * 40 + koff);
      #pragma unroll
      for (int m = 0; m < 2; ++m)
        #pragma unroll
        for (int n = 0; n < 4; ++n)
          acc[m][n] = __builtin_amdgcn_mfma_f32_16x16x32_bf16(av[m], bvv[n], acc[m][n], 0, 0, 0);
    }
    #pragma unroll
    for (int n = 0; n < 4; ++n){
      const int ng = n0 + n * 16 + (lane & 15);
      const float bgv = bg[ng];
      #pragma unroll
      for (int m = 0; m < 2; ++m){
        const int mbase = m0 + wave * 32 + m * 16 + (lane >> 4) * 4;
        #pragma unroll
        for (int r = 0; r < 4; ++r){
          float v = acc[m][n][r] + bgv;
          float s = v / (1.0f + __expf(-v));
          __hip_atomic_store(&houtp[(size_t)(mbase + r + 16) * 2048 + ng], s,
                             __ATOMIC_RELAXED, __HIP_MEMORY_SCOPE_SYSTEM);
        }
      }
    }
    __syncthreads();   // vmcnt(0) drain before flag
    if (tid == 0)
      __hip_atomic_fetch_add(&gcnt[q >> 3], 4, __ATOMIC_RELAXED, __HIP_MEMORY_SCOPE_SYSTEM);
  }
}

extern "C" void kernel_launch(void* const* d_in, const int* in_sizes, int n_in,
                              void* d_out, int out_size, void* d_ws, size_t ws_size,
                              hipStream_t stream){
  const float* x  = (const float*)d_in[0];
  const float* h0 = (const float*)d_in[1];
  const float* ch = (const float*)d_in[2];
  const float* cx = (const float*)d_in[3];
  const float* Wg = (const float*)d_in[4];
  const float* bb = (const float*)d_in[5];
  const float* bg = (const float*)d_in[6];
  float* outp  = (float*)d_out;                        // [T,B,D]
  float* houtp = outp + (size_t)1024 * 16 * 2048;      // [T+1,B,D]

  char* w = (char*)d_ws;
  unsigned short* xb = (unsigned short*)w; w += (size_t)16384 * 2048 * 2;
  unsigned short* Wb = (unsigned short*)w; w += (size_t)2048 * 2048 * 2;
  int* flags = (int*)w; w += 256 * sizeof(int);

  cvt_bf16<<<dim3(16384), dim3(256), 0, stream>>>(x,  xb, 16384 * 2048 / 8);
  cvt_bf16<<<dim3(2048),  dim3(256), 0, stream>>>(Wg, Wb,  2048 * 2048 / 8);
  hipMemsetAsync(flags, 0, 256 * sizeof(int), stream);
  mega<<<dim3(1168), dim3(1024), 0, stream>>>(x, xb, Wb, h0, ch, cx, bb, bg,
                                              outp, houtp, flags);
}

// Round 16
// 1780.632 us; speedup vs baseline: 1.0720x; 1.0720x over previous
//
#include <hip/hip_runtime.h>
#include <hip/hip_bf16.h>

// CirculantElmanCell: T=1024, B=16, D=2048
// out0: output [T,B,D] f32 ; out1: h [T+1,B,D] f32 (concatenated in d_out)

typedef __attribute__((ext_vector_type(8))) unsigned short us8;
typedef __attribute__((ext_vector_type(8))) __bf16 bf16x8;
typedef __attribute__((ext_vector_type(4))) float f32x4;
typedef __attribute__((ext_vector_type(2))) float f32x2;

__device__ __forceinline__ int SIGF(int a){ return a ^ (((a >> 8) & 3) << 2) ^ ((a >> 6) & 3); }
__device__ __forceinline__ int rev2i(int v){ return ((v & 1) << 1) | ((v >> 1) & 1); }
__device__ __forceinline__ int PERMF(int i){
  return rev2i((i >> 8) & 3) | (rev2i((i >> 6) & 3) << 2) | (rev2i((i >> 4) & 3) << 4)
       | (rev2i((i >> 2) & 3) << 6) | (rev2i(i & 3) << 8);
}

// LDS-only barrier: no vmcnt drain (global loads/stores stay in flight)
#define LDSBAR() do { \
  asm volatile("s_waitcnt lgkmcnt(0)\n\ts_barrier" ::: "memory"); \
  __builtin_amdgcn_sched_barrier(0); \
} while (0)

__device__ __forceinline__ unsigned short f2bf(float f){
  unsigned int u = __float_as_uint(f);
  return (unsigned short)((u + 0x7FFFu + ((u >> 16) & 1u)) >> 16);
}

__device__ __forceinline__ void sincos2pi(float fr, float& sn, float& co){
#if __has_builtin(__builtin_amdgcn_sinf) && __has_builtin(__builtin_amdgcn_cosf)
  sn = __builtin_amdgcn_sinf(fr);   // v_sin_f32: revolutions
  co = __builtin_amdgcn_cosf(fr);
#else
  __sincosf(fr * 6.28318530717958647692f, &sn, &co);
#endif
}

__device__ __forceinline__ float2 cmul(float2 a, float2 b){
  return make_float2(a.x*b.x - a.y*b.y, a.x*b.y + a.y*b.x);
}
__device__ __forceinline__ float2 cmulc(float2 a, float2 b){   // a * conj(b)
  return make_float2(a.x*b.x + a.y*b.y, a.y*b.x - a.x*b.y);
}
__device__ __forceinline__ float2 cadd(float2 a, float2 b){ return make_float2(a.x+b.x, a.y+b.y); }
__device__ __forceinline__ float2 csub(float2 a, float2 b){ return make_float2(a.x-b.x, a.y-b.y); }

__device__ __forceinline__ float tanh_fast(float x){
  float e = __expf(2.0f * x);
  return 1.0f - 2.0f / (e + 1.0f);
}

__device__ __forceinline__ float2 wn(int num, float dinv, int sgn){
  float sn, co; sincos2pi((float)num * dinv, sn, co);
  return make_float2(co, sgn > 0 ? sn : -sn);
}

// ---------------- packed-f32 complex primitives (VOP3P, verified R13/R14) ----------------
__device__ __forceinline__ f32x2 tov(float2 a){ f32x2 r; r[0] = a.x; r[1] = a.y; return r; }
__device__ __forceinline__ float2 tof(f32x2 a){ return make_float2(a[0], a[1]); }

__device__ __forceinline__ float2 pk_fma2(float2 a, float2 b, float2 c){
  f32x2 A = tov(a), B = tov(b), C = tov(c), D;
  asm("v_pk_fma_f32 %0, %1, %2, %3" : "=v"(D) : "v"(A), "v"(B), "v"(C));
  return tof(D);
}
__device__ __forceinline__ float2 pk_cmul(float2 C, float2 z){
  f32x2 Cv = tov(C), Zv = tov(z), D;
  asm("v_pk_mul_f32 %0, %1, %2 op_sel:[0,0] op_sel_hi:[1,0]\n\t"
      "v_pk_fma_f32 %0, %1, %2, %0 op_sel:[1,1,0] op_sel_hi:[0,1,1] neg_lo:[1,0,0]"
      : "=&v"(D) : "v"(Cv), "v"(Zv));
  return tof(D);
}
__device__ __forceinline__ void pk_cfma(float2& acc, float2 C, float2 z){
  f32x2 A = tov(acc), Cv = tov(C), Zv = tov(z);
  asm("v_pk_fma_f32 %0, %1, %2, %0 op_sel:[0,0,0] op_sel_hi:[1,0,1]\n\t"
      "v_pk_fma_f32 %0, %1, %2, %0 op_sel:[1,1,0] op_sel_hi:[0,1,1] neg_lo:[1,0,0]"
      : "+v"(A) : "v"(Cv), "v"(Zv));
  acc = tof(A);
}
__device__ __forceinline__ float2 pk_cmulc(float2 V, float2 m){
  f32x2 Vv = tov(V), Mv = tov(m), D;
  asm("v_pk_mul_f32 %0, %1, %2 op_sel:[0,0] op_sel_hi:[1,0]\n\t"
      "v_pk_fma_f32 %0, %1, %2, %0 op_sel:[1,1,0] op_sel_hi:[0,1,1] neg_hi:[1,0,0]"
      : "=&v"(D) : "v"(Vv), "v"(Mv));
  return tof(D);
}
__device__ __forceinline__ void pk_cfmac(float2& acc, float2 V, float2 m){
  f32x2 A = tov(acc), Vv = tov(V), Mv = tov(m);
  asm("v_pk_fma_f32 %0, %1, %2, %0 op_sel:[0,0,0] op_sel_hi:[1,0,1]\n\t"
      "v_pk_fma_f32 %0, %1, %2, %0 op_sel:[1,1,0] op_sel_hi:[0,1,1] neg_hi:[1,0,0]"
      : "+v"(A) : "v"(Vv), "v"(Mv));
  acc = tof(A);
}

// ---------------- cross-lane exchange primitives ----------------
template<int CTRL>
__device__ __forceinline__ float2 dpp2(float2 v){
  float2 r;
  r.x = __int_as_float(__builtin_amdgcn_mov_dpp(__float_as_int(v.x), CTRL, 0xF, 0xF, true));
  r.y = __int_as_float(__builtin_amdgcn_mov_dpp(__float_as_int(v.y), CTRL, 0xF, 0xF, true));
  return r;
}
template<int IMM>
__device__ __forceinline__ float2 swz2(float2 v){
  float2 r;
  r.x = __int_as_float(__builtin_amdgcn_ds_swizzle(__float_as_int(v.x), IMM));
  r.y = __int_as_float(__builtin_amdgcn_ds_swizzle(__float_as_int(v.y), IMM));
  return r;
}
__device__ __forceinline__ float2 bperm2(int addr, float2 v){
  float2 r;
  r.x = __int_as_float(__builtin_amdgcn_ds_bpermute(addr, __float_as_int(v.x)));
  r.y = __int_as_float(__builtin_amdgcn_ds_bpermute(addr, __float_as_int(v.y)));
  return r;
}
#define DPP_XOR1 0xB1  // quad_perm [1,0,3,2]
#define DPP_XOR2 0x4E  // quad_perm [2,3,0,1]

// ---------------- folded butterfly core: packed (verified R13/R14) ----------------
template<int CONJ>
__device__ __forceinline__ float2 fold2(float2 u, float2 v, float2 C1, float2 C2){
  if (!CONJ){
    float2 d = pk_cmul(C1, u);
    pk_cfma(d, C2, v);
    return d;
  } else {
    float2 d = pk_cmulc(u, C1);
    pk_cfmac(d, v, C2);
    return d;
  }
}

template<int POS>
__device__ __forceinline__ float2 lds4f(const float2* buf, int a0, int a1, int a2, int a3,
                                        float2 sBv, float2 C1, float2 C2){
  float2 in0 = buf[a0], in1 = buf[a1], in2 = buf[a2], in3 = buf[a3];
  float2 u = pk_fma2(in2, sBv, in0);
  float2 v = pk_fma2(in3, sBv, in1);
  return fold2<POS>(u, v, C1, C2);
}

template<int POS>
__device__ __forceinline__ float2 lanes3f(float2 T, int bpa,
    float2 sH2v, float2 E1, float2 E2,
    float2 sH3v, float2 F1, float2 F2,
    float2 sH4v, float2 G1, float2 G2){
  { float2 par = bperm2(bpa, T);
    T = pk_fma2(T, sH2v, par);
    float2 p2 = swz2<0x401F>(T);
    T = fold2<POS>(T, p2, E1, E2); }
  { float2 par = swz2<0x201F>(T);
    T = pk_fma2(T, sH3v, par);
    float2 p2 = swz2<0x101F>(T);
    T = fold2<POS>(T, p2, F1, F2); }
  { float2 par = dpp2<DPP_XOR2>(T);
    T = pk_fma2(T, sH4v, par);
    float2 p2 = dpp2<DPP_XOR1>(T);
    T = fold2<POS>(T, p2, G1, G2); }
  return T;
}

// ---------------- per-thread constants ----------------
struct TW {
  float2 A1, A2, B1, B2;
  float2 E1, E2, F1, F2, G1, G2;
  float2 wmd;
  float2 sB0v, sB1v, sH2v, sH3v, sH4v;
  float sB0;
  int sfi, swP, smir, bpa;
  int aA0, aA1, aA2, aA3, aB0, aB1, aB2, aB3;
  int aM0, aM1, aM2, aM3;
};

__device__ __forceinline__ float2 scal(float2 a, float s){ return make_float2(a.x*s, a.y*s); }

__device__ __forceinline__ void make_tw(int i, TW& S){
  const int p0 = rev2i((i >> 8) & 3);
  const int p1 = rev2i((i >> 6) & 3);
  const int p2v = rev2i((i >> 4) & 3);
  const int p3v = rev2i((i >> 2) & 3);
  const float2 tw0 = wn(((i & 255) * p0) & 1023, 1.0f/1024.0f, -1);
  const float2 tw1 = wn(((i & 63) * p1) & 255, 1.0f/256.0f, -1);
  const float2 tw2 = wn(((i & 15) * p2v) & 63, 1.0f/64.0f, -1);
  const float2 tw3 = wn(((i & 3) * p3v) & 15, 1.0f/16.0f, -1);
  S.wmd = wn(i & 2047, 1.0f/2048.0f, -1);
  const float sD0 = (p0 & 2) ? -1.f : 1.f;  const bool sel0 = p0 & 1;
  const float sD1 = (p1 & 2) ? -1.f : 1.f;  const bool sel1 = p1 & 1;
  const float sB0 = (p0 & 1) ? -1.f : 1.f;
  const float sB1 = (p1 & 1) ? -1.f : 1.f;
  S.sB0 = sB0;
  S.sB0v = make_float2(sB0, sB0);
  S.sB1v = make_float2(sB1, sB1);
  const float2 rho0 = sel0 ? make_float2(0.f,-1.f) : make_float2(1.f,0.f);
  const float2 rho1 = sel1 ? make_float2(0.f,-1.f) : make_float2(1.f,0.f);
  S.A1 = tw0; S.A2 = scal(cmul(tw0, rho0), sD0);
  S.B1 = tw1; S.B2 = scal(cmul(tw1, rho1), sD1);
  const bool c02 = (i >> 4) & 1, c12 = (i >> 5) & 1;
  const bool c03 = (i >> 2) & 1, c13 = (i >> 3) & 1;
  const bool c04 = i & 1,        c14 = (i >> 1) & 1;
  const float sH2 = c12 ? -1.f : 1.f;
  const float sH3 = c13 ? -1.f : 1.f;
  const float sH4 = c14 ? -1.f : 1.f;
  S.sH2v = make_float2(sH2, sH2);
  S.sH3v = make_float2(sH3, sH3);
  S.sH4v = make_float2(sH4, sH4);
  {
    const float sL = c02 ? -1.f : 1.f;
    const float2 rho = c12 ? make_float2(0.f,-1.f) : make_float2(1.f,0.f);
    const float2 al = c02 ? scal(rho, sL) : make_float2(1.f,0.f);
    const float2 be = c02 ? make_float2(1.f,0.f) : scal(rho, sL);
    S.E1 = cmul(tw2, al); S.E2 = cmul(tw2, be);
  }
  {
    const float sL = c03 ? -1.f : 1.f;
    const float2 rho = c13 ? make_float2(0.f,-1.f) : make_float2(1.f,0.f);
    const float2 al = c03 ? scal(rho, sL) : make_float2(1.f,0.f);
    const float2 be = c03 ? make_float2(1.f,0.f) : scal(rho, sL);
    S.F1 = cmul(tw3, al); S.F2 = cmul(tw3, be);
  }
  {
    const float sL = c04 ? -1.f : 1.f;
    const float2 rho = c14 ? make_float2(0.f,-1.f) : make_float2(1.f,0.f);
    S.G1 = c04 ? scal(rho, sL) : make_float2(1.f,0.f);
    S.G2 = c04 ? make_float2(1.f,0.f) : scal(rho, sL);
  }
  S.sfi = SIGF(i); S.swP = SIGF(PERMF(i)); S.smir = SIGF((1024 - i) & 1023);
  S.bpa = ((i & 63) ^ 32) << 2;
  const int r256 = i & 255;
  S.aA0 = SIGF(r256); S.aA1 = SIGF(r256 + 256); S.aA2 = SIGF(r256 + 512); S.aA3 = SIGF(r256 + 768);
  const int b64 = (i & ~255) + (i & 63);
  S.aB0 = SIGF(b64); S.aB1 = SIGF(b64 + 64); S.aB2 = SIGF(b64 + 128); S.aB3 = SIGF(b64 + 192);
  S.aM0 = SIGF((1024 - r256) & 1023);
  S.aM1 = SIGF((1024 - (r256 + 256)) & 1023);
  S.aM2 = SIGF((1024 - (r256 + 512)) & 1023);
  S.aM3 = SIGF((1024 - (r256 + 768)) & 1023);
}

// 5-phase conv body (R13/R14-verified). Result at bB[S.sfi]; caller reads, then barriers.
__device__ __forceinline__ void fftconv5(float2* hz, float2* bA, float2* bB,
                                         const TW& S, const float2* U, const float2* V){
  float2 T = lds4f<0>(hz, S.aA0, S.aA1, S.aA2, S.aA3, S.sB0v, S.A1, S.A2);
  bA[S.sfi] = T; LDSBAR();
  T = lds4f<0>(bA, S.aB0, S.aB1, S.aB2, S.aB3, S.sB1v, S.B1, S.B2);
  T = lanes3f<0>(T, S.bpa, S.sH2v, S.E1, S.E2, S.sH3v, S.F1, S.F2, S.sH4v, S.G1, S.G2);
  bB[S.swP] = T; LDSBAR();
  {
    float2 z0 = bB[S.aA0], z1 = bB[S.aA1], z2 = bB[S.aA2], z3 = bB[S.aA3];
    float2 m0 = bB[S.aM0], m1 = bB[S.aM1], m2 = bB[S.aM2], m3 = bB[S.aM3];
    float2 y = pk_cmul(U[0], z0);
    pk_cfma(y, U[1], z1);
    pk_cfma(y, U[2], z2);
    pk_cfma(y, U[3], z3);
    pk_cfmac(y, V[0], m0);
    pk_cfmac(y, V[1], m1);
    pk_cfmac(y, V[2], m2);
    pk_cfmac(y, V[3], m3);
    bA[S.sfi] = y;
  }
  LDSBAR();
  T = lds4f<1>(bA, S.aB0, S.aB1, S.aB2, S.aB3, S.sB1v, S.B1, S.B2);
  T = lanes3f<1>(T, S.bpa, S.sH2v, S.E1, S.E2, S.sH3v, S.F1, S.F2, S.sH4v, S.G1, S.G2);
  bB[S.swP] = T; LDSBAR();
}

// in-block lam + P/Q from real 2048-seq c (verified R9-R14)
__device__ __forceinline__ void make_PQ(const float* __restrict__ c, int i, const TW& S,
                                        float2* hz, float2* bA, float2* bB,
                                        float2& P, float2& Q){
  hz[S.sfi] = ((const float2*)c)[i];
  __syncthreads();
  float2 T = lds4f<0>(hz, S.aA0, S.aA1, S.aA2, S.aA3, S.sB0v, S.A1, S.A2);
  bA[S.sfi] = T;
  __syncthreads();
  T = lds4f<0>(bA, S.aB0, S.aB1, S.aB2, S.aB3, S.sB1v, S.B1, S.B2);
  T = lanes3f<0>(T, S.bpa, S.sH2v, S.E1, S.E2, S.sH3v, S.F1, S.F2, S.sH4v, S.G1, S.G2);
  bB[S.swP] = T;
  __syncthreads();
  float2 zk = bB[S.sfi], zp = bB[S.smir];
  float2 E = make_float2(0.5f*(zk.x+zp.x),  0.5f*(zk.y-zp.y));
  float2 O = make_float2(0.5f*(zk.y+zp.y), -0.5f*(zk.x-zp.x));
  float2 w = S.wmd;
  float2 wO = cmul(w, O);
  float2 lamA = scal(cadd(E, wO), 1.0f/2048.0f);
  float2 lamB = scal(csub(E, wO), 1.0f/2048.0f);
  float2 al = make_float2(0.5f*(1.0f + w.y), -0.5f*w.x);
  float2 be = make_float2(0.5f*(1.0f - w.y),  0.5f*w.x);
  float2 ga = make_float2(1.0f + w.y,  w.x);
  float2 de = make_float2(1.0f - w.y, -w.x);
  float2 gA = cmul(ga, lamA), dB = cmul(de, lamB);
  P = cadd(cmul(gA, al), cmul(dB, be));
  Q = cadd(cmul(gA, be), cmul(dB, al));
  __syncthreads();
}

// stage P,Q through LDS and gather per-thread U/V for the fused phase
__device__ __forceinline__ void make_UV(int i, const TW& S, float2 P, float2 Q,
                                        float2* bA, float2* bB, float2* U, float2* V){
  ((float2*)bB)[i] = P;
  ((float2*)bA)[i] = Q;
  __syncthreads();
  const int r256 = i & 255;
  const float2 cA1 = make_float2(S.A1.x, -S.A1.y);
  const float2 cA2 = make_float2(S.A2.x, -S.A2.y);
  float2 cc[4];
  cc[0] = cA1; cc[1] = cA2; cc[2] = scal(cA1, S.sB0); cc[3] = scal(cA2, S.sB0);
  #pragma unroll
  for (int q = 0; q < 4; ++q){
    const int n = r256 + 256 * q;
    U[q] = cmul(cc[q], ((float2*)bB)[n]);
    V[q] = cmul(cc[q], ((float2*)bA)[n]);
  }
  __syncthreads();
}

// ---------------- f32 -> bf16 bulk convert (R8-proven) ----------------
__global__ __launch_bounds__(256) void cvt_bf16(const float* __restrict__ in,
                                                unsigned short* __restrict__ out, int n8){
  int i = blockIdx.x * 256 + threadIdx.x;
  if (i >= n8) return;
  float4 a = ((const float4*)in)[2 * i];
  float4 b = ((const float4*)in)[2 * i + 1];
  us8 r;
  r[0] = f2bf(a.x); r[1] = f2bf(a.y); r[2] = f2bf(a.z); r[3] = f2bf(a.w);
  r[4] = f2bf(b.x); r[5] = f2bf(b.y); r[6] = f2bf(b.z); r[7] = f2bf(b.w);
  ((us8*)out)[i] = r;
}

// =====================================================================
// mega v9 (R14 best-known config, byte-exact revert of R15's permlane change).
// blocks [0,16) recur ; [16,144) circx ; [144,1168) gemm (4 tiles each, bf16).
// =====================================================================
__global__ __launch_bounds__(1024, 4) void mega(
    const float* __restrict__ x, const unsigned short* __restrict__ xb,
    const unsigned short* __restrict__ Wb, const float* __restrict__ h0,
    const float* __restrict__ ch, const float* __restrict__ cx,
    const float* __restrict__ bias, const float* __restrict__ bg,
    float* __restrict__ outp, float* __restrict__ houtp, int* __restrict__ flags){
  __shared__ __align__(16) char smem[98304];   // 96KB: forces 1 block/CU
  const int bid = blockIdx.x;
  const int tid = threadIdx.x;
  int* gcnt = flags;
  int* wcnt = flags + 128;

  if (bid < 16){
    // ---------------- recur consumer (dedicated CU) ----------------
    float2* hz = (float2*)smem; float2* bA = hz + 1024; float2* bB = hz + 2048;
    const int i = tid, b = bid;
    TW S; make_tw(i, S);
    float2 P, Q; make_PQ(ch, i, S, hz, bA, bB, P, Q);
    float2 U[4], V[4]; make_UV(i, S, P, Q, bA, bB, U, V);
    {
      const float2* h02 = (const float2*)(h0 + (size_t)b * 2048);
      float2* hrow0 = (float2*)(houtp + (size_t)b * 2048);
      float2 v = h02[i]; hz[S.sfi] = v; hrow0[i] = v;
    }
    __syncthreads();
    int pg = 0, pw = 0;   // prefetched flag values (tid0 only)
    #pragma unroll 1
    for (int t = 0; t < 1024; ++t){
      if ((t & 7) == 0){
        if (tid == 0){
          const int xk = t >> 3;
          while (pg < 32){
            pg = __hip_atomic_load(&gcnt[xk], __ATOMIC_RELAXED, __HIP_MEMORY_SCOPE_SYSTEM);
            if (pg < 32) __builtin_amdgcn_s_sleep(16);
          }
          while (pw < 128){
            pw = __hip_atomic_load(&wcnt[xk], __ATOMIC_RELAXED, __HIP_MEMORY_SCOPE_SYSTEM);
            if (pw < 128) __builtin_amdgcn_s_sleep(16);
          }
          if (xk < 127){   // prefetch next chunk; latency hides across 8 steps
            pg = __hip_atomic_load(&gcnt[xk + 1], __ATOMIC_RELAXED, __HIP_MEMORY_SCOPE_SYSTEM);
            pw = __hip_atomic_load(&wcnt[xk + 1], __ATOMIC_RELAXED, __HIP_MEMORY_SCOPE_SYSTEM);
          }
        }
        __syncthreads();
      }
      float* orow = outp  + ((size_t)t * 16 + b) * 2048;
      float* hrow = houtp + ((size_t)(t + 1) * 16 + b) * 2048;
      // single 8B system-scope (L2-bypass) loads
      unsigned long long pv = __hip_atomic_load((const unsigned long long*)(orow + 2*i),
                                                __ATOMIC_RELAXED, __HIP_MEMORY_SCOPE_SYSTEM);
      unsigned long long gvv = __hip_atomic_load((const unsigned long long*)(hrow + 2*i),
                                                 __ATOMIC_RELAXED, __HIP_MEMORY_SCOPE_SYSTEM);
      float2 pr = __builtin_bit_cast(float2, pv);
      float2 gv = __builtin_bit_cast(float2, gvv);
      fftconv5(hz, bA, bB, S, U, V);
      float2 y = bB[S.sfi];
      float hx = tanh_fast(y.x + pr.x);
      float hy = tanh_fast(y.y + pr.y);
      float ox = hx * gv.x, oy = hy * gv.y;
      asm volatile("" : "+v"(hx), "+v"(hy) : "v"(gv.x), "v"(gv.y));
      float2 hv = make_float2(hx, hy);
      hz[S.sfi] = hv;
      *(float2*)(hrow + 2 * i) = hv;
      *(float2*)(orow + 2 * i) = make_float2(ox, oy);
      LDSBAR();
    }
  } else if (bid < 144){
    // ---------------- circx producer: rows cblk + 128*k ----------------
    float2* hz = (float2*)smem; float2* bA = hz + 1024; float2* bB = hz + 2048;
    const int i = tid, cblk = bid - 16;
    TW S; make_tw(i, S);
    float2 P, Q; make_PQ(cx, i, S, hz, bA, bB, P, Q);
    float2 U[4], V[4]; make_UV(i, S, P, Q, bA, bB, U, V);
    const float2 bv = ((const float2*)bias)[i];
    #pragma unroll 1
    for (int k = 0; k < 128; ++k){
      const size_t row = (size_t)cblk + ((size_t)k << 7);
      hz[S.sfi] = ((const float2*)(x + row * 2048))[i];
      LDSBAR();
      fftconv5(hz, bA, bB, S, U, V);
      float2 y = bB[S.sfi];
      float* pd = outp + row * 2048 + 2 * i;
      float2 yv = make_float2(y.x + bv.x, y.y + bv.y);
      __hip_atomic_store((unsigned long long*)pd, __builtin_bit_cast(unsigned long long, yv),
                         __ATOMIC_RELAXED, __HIP_MEMORY_SCOPE_SYSTEM);
      __syncthreads();   // vmcnt(0) drain: stores complete at L3 before flag
      if (tid == 0)
        __hip_atomic_fetch_add(&wcnt[k], 1, __ATOMIC_RELAXED, __HIP_MEMORY_SCOPE_SYSTEM);
    }
  } else {
    // ---------------- gemm producer: 4 tiles 128x64, bf16, LDA=40 pad (R8-proven) ----------------
    const int q = bid - 144;
    const int g = tid >> 8, tid8 = tid & 255;
    const int tau = q * 4 + g;
    const int m0 = (tau >> 5) * 128, n0 = (tau & 31) * 64;
    unsigned short* As = (unsigned short*)(smem + g * 15360);   // 128 x 40 (padded)
    unsigned short* Bs = As + 5120;                             // 64 x 40
    const int lane = tid8 & 63, wave = tid8 >> 6;
    const int srA = tid8 >> 1, scA = (tid8 & 1) << 4;
    const int srB = tid8 >> 2, scB = (tid8 & 3) << 3;
    const unsigned short* ga = xb + (size_t)(m0 + srA) * 2048 + scA;
    const unsigned short* gb = Wb + (size_t)(n0 + srB) * 2048 + scB;
    unsigned short* la = As + srA * 40 + scA;
    unsigned short* lb = Bs + srB * 40 + scB;
    f32x4 acc[2][4];
    #pragma unroll
    for (int m = 0; m < 2; ++m)
      #pragma unroll
      for (int n = 0; n < 4; ++n)
        acc[m][n] = f32x4{0.f, 0.f, 0.f, 0.f};
    const int arow = wave * 32 + (lane & 15);
    const int brow = lane & 15;
    const int koff = (lane >> 4) * 8;
    for (int ks = 0; ks < 64; ++ks){
      const int k0 = ks * 32;
      us8 va0 = *(const us8*)(ga + k0);
      us8 va1 = *(const us8*)(ga + k0 + 8);
      us8 vb0 = *(const us8*)(gb + k0);
      __syncthreads();
      *(us8*)(la)     = va0; *(us8*)(la + 8) = va1;
      *(us8*)(lb)     = vb0;
      __syncthreads();
      bf16x8 av[2], bvv[4];
      #pragma unroll
      for (int m = 0; m < 2; ++m) av[m] = *(const bf16x8*)(As + (arow + m * 16) * 40 + koff);
      #pragma unroll
      for (int n = 0; n < 4; ++n) bvv[n] = *(const bf16x8*)(Bs + (brow + n * 16) * 40 + koff);
      #pragma unroll
      for (int m = 0; m < 2; ++m)
        #pragma unroll
        for (int n = 0; n < 4; ++n)
          acc[m][n] = __builtin_amdgcn_mfma_f32_16x16x32_bf16(av[m], bvv[n], acc[m][n], 0, 0, 0);
    }
    #pragma unroll
    for (int n = 0; n < 4; ++n){
      const int ng = n0 + n * 16 + (lane & 15);
      const float bgv = bg[ng];
      #pragma unroll
      for (int m = 0; m < 2; ++m){
        const int mbase = m0 + wave * 32 + m * 16 + (lane >> 4) * 4;
        #pragma unroll
        for (int r = 0; r < 4; ++r){
          float v = acc[m][n][r] + bgv;
          float s = v / (1.0f + __expf(-v));
          __hip_atomic_store(&houtp[(size_t)(mbase + r + 16) * 2048 + ng], s,
                             __ATOMIC_RELAXED, __HIP_MEMORY_SCOPE_SYSTEM);
        }
      }
    }
    __syncthreads();   // vmcnt(0) drain before flag
    if (tid == 0)
      __hip_atomic_fetch_add(&gcnt[q >> 3], 4, __ATOMIC_RELAXED, __HIP_MEMORY_SCOPE_SYSTEM);
  }
}

extern "C" void kernel_launch(void* const* d_in, const int* in_sizes, int n_in,
                              void* d_out, int out_size, void* d_ws, size_t ws_size,
                              hipStream_t stream){
  const float* x  = (const float*)d_in[0];
  const float* h0 = (const float*)d_in[1];
  const float* ch = (const float*)d_in[2];
  const float* cx = (const float*)d_in[3];
  const float* Wg = (const float*)d_in[4];
  const float* bb = (const float*)d_in[5];
  const float* bg = (const float*)d_in[6];
  float* outp  = (float*)d_out;                        // [T,B,D]
  float* houtp = outp + (size_t)1024 * 16 * 2048;      // [T+1,B,D]

  char* w = (char*)d_ws;
  unsigned short* xb = (unsigned short*)w; w += (size_t)16384 * 2048 * 2;
  unsigned short* Wb = (unsigned short*)w; w += (size_t)2048 * 2048 * 2;
  int* flags = (int*)w; w += 256 * sizeof(int);

  cvt_bf16<<<dim3(16384), dim3(256), 0, stream>>>(x,  xb, 16384 * 2048 / 8);
  cvt_bf16<<<dim3(2048),  dim3(256), 0, stream>>>(Wg, Wb,  2048 * 2048 / 8);
  hipMemsetAsync(flags, 0, 256 * sizeof(int), stream);
  mega<<<dim3(1168), dim3(1024), 0, stream>>>(x, xb, Wb, h0, ch, cx, bb, bg,
                                              outp, houtp, flags);
}